// Round 1
// baseline (17340.146 us; speedup 1.0000x reference)
//
#include <hip/hip_runtime.h>
#include <hip/hip_bf16.h>
#include <hip/hip_fp16.h>

#define VOCABN 50257
#define EMBEDN 256
#define HIDDENN 256
#define TAGSN 8192
#define SEQN 8192

typedef _Float16 f16x2 __attribute__((ext_vector_type(2)));

__device__ __forceinline__ float fdot2(f16x2 a, f16x2 b, float c) {
#if __has_builtin(__builtin_amdgcn_fdot2)
    return __builtin_amdgcn_fdot2(a, b, c, false);
#else
    return c + (float)a[0] * (float)b[0] + (float)a[1] * (float)b[1];
#endif
}

__device__ __forceinline__ f16x2 bc16(unsigned int u) {
    return __builtin_bit_cast(f16x2, u);
}

__device__ __forceinline__ float sigm(float x) {
    x = fminf(fmaxf(x, -30.f), 30.f);
    return 1.f / (1.f + __expf(-x));
}

__device__ __forceinline__ float tanh_f(float x) {
    x = fminf(fmaxf(x, -15.f), 15.f);
    float e = __expf(-2.f * x);
    return (1.f - e) / (1.f + e);
}

// ---------------------------------------------------------------------------
// prep: WxT[k][o] = W_gate(o)[o&255][k]  (transposed x-part for coalesced GEMM)
//       bcat[o]   = b_gate(o)[o&255]
// ---------------------------------------------------------------------------
__global__ __launch_bounds__(256) void prep_kernel(
    const float* __restrict__ Wf, const float* __restrict__ Wi,
    const float* __restrict__ Wg, const float* __restrict__ Wo,
    const float* __restrict__ bf, const float* __restrict__ bi,
    const float* __restrict__ bg, const float* __restrict__ bo,
    float* __restrict__ WxT, float* __restrict__ bcat)
{
    int idx = blockIdx.x * 256 + threadIdx.x;   // 0..262143
    int k = idx >> 10, o = idx & 1023;
    int g = o >> 8, r = o & 255;
    const float* W = (g == 0) ? Wf : (g == 1) ? Wi : (g == 2) ? Wg : Wo;
    WxT[idx] = W[r * 512 + k];
    if (idx < 1024) {
        const float* b = (g == 0) ? bf : (g == 1) ? bi : (g == 2) ? bg : bo;
        bcat[idx] = b[r];
    }
}

// ---------------------------------------------------------------------------
// xproj[s][o] = sum_k emb[sentence[s]][k] * WxT[k][o] + bcat[o]
// block: 256 threads = 256 outputs (o), 32 steps per block
// ---------------------------------------------------------------------------
__global__ __launch_bounds__(256) void xproj_kernel(
    const int* __restrict__ sentence, const float* __restrict__ emb,
    const float* __restrict__ WxT, const float* __restrict__ bcat,
    float* __restrict__ xproj)
{
    __shared__ __align__(16) float At[32 * 256];
    const int tid = threadIdx.x;
    const int s0 = blockIdx.y * 32;
    const int o = blockIdx.x * 256 + tid;

#pragma unroll
    for (int i = 0; i < 32; i++) {
        int idx = tid + i * 256;
        int srow = idx >> 8, c = idx & 255;
        At[idx] = emb[(size_t)sentence[s0 + srow] * 256 + c];
    }
    __syncthreads();

    float acc[32];
    float b = bcat[o];
#pragma unroll
    for (int i = 0; i < 32; i++) acc[i] = b;

    for (int k4 = 0; k4 < 64; k4++) {
        float4 w;
        w.x = WxT[(k4 * 4 + 0) * 1024 + o];
        w.y = WxT[(k4 * 4 + 1) * 1024 + o];
        w.z = WxT[(k4 * 4 + 2) * 1024 + o];
        w.w = WxT[(k4 * 4 + 3) * 1024 + o];
#pragma unroll
        for (int i = 0; i < 32; i++) {
            float4 a = *(const float4*)&At[i * 256 + k4 * 4];
            acc[i] += a.x * w.x + a.y * w.y + a.z * w.z + a.w * w.w;
        }
    }
#pragma unroll
    for (int i = 0; i < 32; i++)
        xproj[(size_t)(s0 + i) * 1024 + o] = acc[i];
}

// ---------------------------------------------------------------------------
// Persistent single-workgroup LSTM. 1024 threads; thread t owns gate-output t
// (f:0-255, i:256-511, g:512-767, o:768-1023). Recurrent weights (f16):
// k in [0,192) in 96 packed VGPRs, k in [192,256) in LDS chunk-major.
// ---------------------------------------------------------------------------
__global__ __launch_bounds__(1024, 4) void lstm_kernel(
    const float* __restrict__ Wf, const float* __restrict__ Wi,
    const float* __restrict__ Wg, const float* __restrict__ Wo,
    const float* __restrict__ xproj, float* __restrict__ h_all)
{
    __shared__ uint4 wldsT[8][1024];              // 128 KiB, chunk-major: conflict-free b128
    __shared__ float gates[1024];                 // 4 KiB
    __shared__ __align__(16) _Float16 hbuf[2][256]; // 1 KiB double-buffered h (f16)

    const int t = threadIdx.x;
    const int gate = t >> 8, r = t & 255;
    const float* W = (gate == 0) ? Wf : (gate == 1) ? Wi : (gate == 2) ? Wg : Wo;
    const float* wrow = W + r * 512 + 256;        // h-part of the row

    // ---- one-time setup: weights to VGPRs (k<192) and LDS (k>=192) ----
    f16x2 wr[96];
#pragma unroll
    for (int j = 0; j < 96; j++) {
        float2 w2 = ((const float2*)wrow)[j];     // k = 2j, 2j+1
        f16x2 p = { (_Float16)w2.x, (_Float16)w2.y };
        wr[j] = p;
    }
#pragma unroll
    for (int c = 0; c < 8; c++) {                 // chunk c = halves [192+8c, 192+8c+8)
        uint4 u;
        unsigned int* up = (unsigned int*)&u;
#pragma unroll
        for (int q = 0; q < 4; q++) {
            float2 w2 = ((const float2*)wrow)[96 + c * 4 + q];
            f16x2 p = { (_Float16)w2.x, (_Float16)w2.y };
            up[q] = __builtin_bit_cast(unsigned int, p);
        }
        wldsT[c][t] = u;
    }
    if (t < 256) { hbuf[0][t] = (_Float16)0.f; hbuf[1][t] = (_Float16)0.f; }
    float cst = 0.f;
    __syncthreads();

    const float* xp_ptr = xproj + t;
    for (int s = 0; s < SEQN; ++s) {
        float xp = xp_ptr[s * 1024];              // prefetched by compiler across dot phase
        const uint4* hv = (const uint4*)hbuf[s & 1];
        float a0 = 0.f, a1 = 0.f, a2 = 0.f, a3 = 0.f;
#pragma unroll
        for (int c = 0; c < 24; c++) {            // k in [0,192): register weights
            uint4 h4 = hv[c];
            a0 = fdot2(wr[4 * c + 0], bc16(h4.x), a0);
            a1 = fdot2(wr[4 * c + 1], bc16(h4.y), a1);
            a2 = fdot2(wr[4 * c + 2], bc16(h4.z), a2);
            a3 = fdot2(wr[4 * c + 3], bc16(h4.w), a3);
        }
#pragma unroll
        for (int c = 0; c < 8; c++) {             // k in [192,256): LDS weights
            uint4 h4 = hv[24 + c];
            uint4 w4 = wldsT[c][t];
            a0 = fdot2(bc16(w4.x), bc16(h4.x), a0);
            a1 = fdot2(bc16(w4.y), bc16(h4.y), a1);
            a2 = fdot2(bc16(w4.z), bc16(h4.z), a2);
            a3 = fdot2(bc16(w4.w), bc16(h4.w), a3);
        }
        float a = (a0 + a1) + (a2 + a3) + xp;
        float act = (gate == 2) ? tanh_f(a) : sigm(a);
        gates[t] = act;
        __syncthreads();
        if (t < 256) {
            float fg = gates[t], ig = gates[t + 256], gg = gates[t + 512], og = gates[t + 768];
            cst = fg * cst + ig * gg;
            float h = og * tanh_f(cst);
            h_all[s * 256 + t] = h;
            hbuf[(s + 1) & 1][t] = (_Float16)h;
        }
        __syncthreads();
    }
}

// ---------------------------------------------------------------------------
// logits[t][v] = h_all[t] . Wtag[v] + btag[v]   (64x64 tile / block, 4x4 micro)
// ---------------------------------------------------------------------------
__global__ __launch_bounds__(256) void logits_kernel(
    const float* __restrict__ h_all, const float* __restrict__ Wtag,
    const float* __restrict__ btag, float* __restrict__ out)
{
    __shared__ __align__(16) float At[64 * 68];   // stride 68 floats = 272 B (16B-mult, bank-friendly)
    __shared__ __align__(16) float Bt[64 * 68];
    const int tid = threadIdx.x;
    const int tx = tid & 15, ty = tid >> 4;
    const int t0 = blockIdx.y * 64, v0 = blockIdx.x * 64;
    float acc[4][4] = {};

    for (int kc = 0; kc < 256; kc += 64) {
        __syncthreads();
#pragma unroll
        for (int i = 0; i < 16; i++) {
            int idx = tid + i * 256;              // 0..4095
            int rrow = idx >> 6, ccol = idx & 63;
            At[rrow * 68 + ccol] = h_all[(t0 + rrow) * 256 + kc + ccol];
            Bt[rrow * 68 + ccol] = Wtag[(size_t)(v0 + rrow) * 256 + kc + ccol];
        }
        __syncthreads();
#pragma unroll
        for (int k4 = 0; k4 < 16; k4++) {
            float4 av[4], bv[4];
#pragma unroll
            for (int i = 0; i < 4; i++) av[i] = *(const float4*)&At[(ty + 16 * i) * 68 + k4 * 4];
#pragma unroll
            for (int j = 0; j < 4; j++) bv[j] = *(const float4*)&Bt[(tx + 16 * j) * 68 + k4 * 4];
#pragma unroll
            for (int i = 0; i < 4; i++)
#pragma unroll
                for (int j = 0; j < 4; j++)
                    acc[i][j] += av[i].x * bv[j].x + av[i].y * bv[j].y +
                                 av[i].z * bv[j].z + av[i].w * bv[j].w;
        }
    }
#pragma unroll
    for (int j = 0; j < 4; j++) {
        float bb = btag[v0 + tx + 16 * j];
#pragma unroll
        for (int i = 0; i < 4; i++) {
            out[(size_t)(t0 + ty + 16 * i) * TAGSN + v0 + tx + 16 * j] = acc[i][j] + bb;
        }
    }
}

// ---------------------------------------------------------------------------
// in-place row-wise log_softmax over 8192 columns (one block per row)
// ---------------------------------------------------------------------------
__global__ __launch_bounds__(256) void lsm_kernel(float* __restrict__ out)
{
    const int row = blockIdx.x, tid = threadIdx.x;
    float* p = out + (size_t)row * TAGSN;
    float v[32];
#pragma unroll
    for (int j = 0; j < 32; j++) v[j] = p[tid + 256 * j];

    float m = -1e30f;
#pragma unroll
    for (int j = 0; j < 32; j++) m = fmaxf(m, v[j]);
#pragma unroll
    for (int off = 32; off; off >>= 1) m = fmaxf(m, __shfl_xor(m, off, 64));
    __shared__ float red[4];
    if ((tid & 63) == 0) red[tid >> 6] = m;
    __syncthreads();
    m = fmaxf(fmaxf(red[0], red[1]), fmaxf(red[2], red[3]));

    float s = 0.f;
#pragma unroll
    for (int j = 0; j < 32; j++) s += __expf(v[j] - m);
#pragma unroll
    for (int off = 32; off; off >>= 1) s += __shfl_xor(s, off, 64);
    __shared__ float red2[4];
    if ((tid & 63) == 0) red2[tid >> 6] = s;
    __syncthreads();
    s = (red2[0] + red2[1]) + (red2[2] + red2[3]);

    float lse = m + __logf(s);
#pragma unroll
    for (int j = 0; j < 32; j++) p[tid + 256 * j] = v[j] - lse;
}

// ---------------------------------------------------------------------------
extern "C" void kernel_launch(void* const* d_in, const int* in_sizes, int n_in,
                              void* d_out, int out_size, void* d_ws, size_t ws_size,
                              hipStream_t stream)
{
    const int*   sentence = (const int*)d_in[0];
    const float* emb  = (const float*)d_in[1];
    const float* Wf   = (const float*)d_in[2];
    const float* bf   = (const float*)d_in[3];
    const float* Wi   = (const float*)d_in[4];
    const float* bi   = (const float*)d_in[5];
    const float* Wg   = (const float*)d_in[6];
    const float* bg   = (const float*)d_in[7];
    const float* Wo   = (const float*)d_in[8];
    const float* bo   = (const float*)d_in[9];
    const float* Wtag = (const float*)d_in[10];
    const float* btag = (const float*)d_in[11];
    float* out = (float*)d_out;

    char* ws = (char*)d_ws;
    float* WxT   = (float*)(ws);                                      // 1 MiB
    float* bcat  = (float*)(ws + (1u << 20));                         // 4 KiB
    float* xproj = (float*)(ws + (1u << 20) + (1u << 16));            // 32 MiB
    float* h_all = (float*)(ws + (1u << 20) + (1u << 16) + (32u << 20)); // 8 MiB

    prep_kernel<<<1024, 256, 0, stream>>>(Wf, Wi, Wg, Wo, bf, bi, bg, bo, WxT, bcat);
    xproj_kernel<<<dim3(4, 256), 256, 0, stream>>>(sentence, emb, WxT, bcat, xproj);
    lstm_kernel<<<1, 1024, 0, stream>>>(Wf, Wi, Wg, Wo, xproj, h_all);
    logits_kernel<<<dim3(128, 128), 256, 0, stream>>>(h_all, Wtag, btag, out);
    lsm_kernel<<<8192, 256, 0, stream>>>(out);
}